// Round 5
// baseline (345.182 us; speedup 1.0000x reference)
//
#include <hip/hip_runtime.h>
#include <hip/hip_bf16.h>
#include <stdint.h>

// Problem constants (B=4096, D=2048, K=8, H2=64)
#define NB 4096
#define ND 2048
#define NK 8
#define NH 64

// GEMM tile: 128x128, BK=32, 16x16x32 bf16 MFMA, 256 threads (4 waves, 2x2).
// Depth-1 double-buffer prefetch: STAGE(t+1) issued BEFORE COMPUTE(t); the
// trailing __syncthreads (vmcnt(0)+lgkmcnt(0)+barrier) drains it, so load
// latency hides under the compute phase. Four separate __shared__ arrays +
// 2x-unrolled loop -> all LDS addresses compile-time constant (no rotation
// VALU, the R2 failure mode).
#define BM 128
#define BN 128
#define BK 32
#define MAX_ROWS 5120   // 4096 + 8*127 padding worst case
#define MAX_TILES 40

// fused prep grid partition: 2048 fat convert blocks + 16 kidx blocks
#define CONV_BLOCKS  2048
#define KIDX_BLOCKS  (NB / 256)    // 16: kidx + per-block histogram
#define PREP_GRID    (CONV_BLOCKS + KIDX_BLOCKS)
// W1 = 16384*2048 floats = 33,554,432 = 4 stripes of 8,388,608
// x  =  4096*2048 floats =  8,388,608 = 1 stripe
#define STRIPE 8388608

typedef __bf16 bf16;
typedef __bf16 bf16x8 __attribute__((ext_vector_type(8)));
typedef float floatx4 __attribute__((ext_vector_type(4)));

// Workspace layout (bytes)
#define OFF_KIDX   0u          // 4096 int
#define OFF_ORDER  16384u      // 5120 int (padding slots stay poisoned -> negative)
#define OFF_META   40960u      // 81 ints: [0]=n_mt, [1..40]=branch, [41..80]=row0
#define OFF_CUR    41472u      // 8 int cursors
#define OFF_C2S    41536u      // 8 float
#define OFF_CNTP   41600u      // 16*8 int per-block partial counts
#define OFF_XC     65536u      // 4096*2048 bf16 = 16777216 B
#define OFF_WB     16842752u   // 16384*2048 bf16 = 67108864 B (W1 row order, bf16)

// Convert 16 consecutive floats -> 16 bf16. Non-temporal reads: fp32 source is
// single-use; keep L3 for the bf16 outputs which the GEMM re-reads.
__device__ inline void cvt16nt(const float* __restrict__ src, bf16* __restrict__ dst) {
    floatx4 a = __builtin_nontemporal_load((const floatx4*)src);
    floatx4 b = __builtin_nontemporal_load((const floatx4*)src + 1);
    floatx4 c = __builtin_nontemporal_load((const floatx4*)src + 2);
    floatx4 d = __builtin_nontemporal_load((const floatx4*)src + 3);
    bf16x8 v0, v1;
    v0[0] = (bf16)a[0]; v0[1] = (bf16)a[1]; v0[2] = (bf16)a[2]; v0[3] = (bf16)a[3];
    v0[4] = (bf16)b[0]; v0[5] = (bf16)b[1]; v0[6] = (bf16)b[2]; v0[7] = (bf16)b[3];
    v1[0] = (bf16)c[0]; v1[1] = (bf16)c[1]; v1[2] = (bf16)c[2]; v1[3] = (bf16)c[3];
    v1[4] = (bf16)d[0]; v1[5] = (bf16)d[1]; v1[6] = (bf16)d[2]; v1[7] = (bf16)d[3];
    *(bf16x8*)dst = v0;
    *((bf16x8*)dst + 1) = v1;
}

// ---------------------------------------------------------------------------
// Dispatch 1 (fused, order-independent): W1->Wb bf16 (SAME row order, pure
// linear stream), x->xc bf16, kidx + per-block branch histograms.
// ---------------------------------------------------------------------------
__global__ void __launch_bounds__(256)
prep_conv_kernel(const float* __restrict__ x,
                 const float* __restrict__ intention,
                 const float* __restrict__ W1,
                 int* __restrict__ kidx,
                 int* __restrict__ cntp,
                 bf16* __restrict__ xc,
                 bf16* __restrict__ Wb)
{
    const int blk = blockIdx.x;
    const int tid = threadIdx.x;

    if (blk < CONV_BLOCKS) {
        const size_t t16 = ((size_t)blk * 256 + tid) * 16;
#pragma unroll
        for (int i = 0; i < 4; i++)
            cvt16nt(W1 + (size_t)i * STRIPE + t16, Wb + (size_t)i * STRIPE + t16);
        cvt16nt(x + t16, xc + t16);
    } else {
        __shared__ int h[NK];
        const int hb = blk - CONV_BLOCKS;                  // 0..15
        if (tid < NK) h[tid] = 0;
        __syncthreads();
        const int b = hb * 256 + tid;
        float4 a = *(const float4*)(intention + (size_t)b * NK);
        float4 c = *(const float4*)(intention + (size_t)b * NK + 4);
        int k = 0;
        if (a.y > 0.5f) k = 1;
        if (a.z > 0.5f) k = 2;
        if (a.w > 0.5f) k = 3;
        if (c.x > 0.5f) k = 4;
        if (c.y > 0.5f) k = 5;
        if (c.z > 0.5f) k = 6;
        if (c.w > 0.5f) k = 7;
        kidx[b] = k;
        atomicAdd(&h[k], 1);
        __syncthreads();
        if (tid < NK) cntp[hb * NK + tid] = h[tid];
    }
}

// ---------------------------------------------------------------------------
// Dispatch 2: single small block. Sum partial counts, build M-tile table +
// branch base cursors; wave 1 computes c2s[k] = b3 + sum_h relu(W2+b2)*W3.
// ---------------------------------------------------------------------------
__global__ void __launch_bounds__(256)
meta_kernel(const int* __restrict__ cntp,
            const float* __restrict__ W2,
            const float* __restrict__ b2,
            const float* __restrict__ W3,
            const float* __restrict__ b3,
            int* __restrict__ meta,
            int* __restrict__ cursors,
            float* __restrict__ c2s)
{
    __shared__ int cnt[NK];
    const int tid = threadIdx.x;
    if (tid < NK) {
        int s = 0;
#pragma unroll
        for (int i = 0; i < KIDX_BLOCKS; i++) s += cntp[i * NK + tid];
        cnt[tid] = s;
    }
    if (tid >= 64 && tid < 128) {
        const int l = tid - 64;
        const int k = l & 7;
        const int hc = l >> 3;
        float s = 0.f;
#pragma unroll
        for (int j = 0; j < 8; j++) {
            int h = hc * 8 + j;
            float v = W2[h * NK + k] + b2[h];
            if (v > 0.f) s += v * W3[ND + h];
        }
        s += __shfl_xor(s, 8, 64);
        s += __shfl_xor(s, 16, 64);
        s += __shfl_xor(s, 32, 64);
        if (l < 8) c2s[k] = s + b3[0];
    }
    __syncthreads();
    if (tid == 0) {
        int running = 0, nt = 0;
        for (int k = 0; k < NK; k++) {
            cursors[k] = running;
            int ntile = (cnt[k] + BM - 1) / BM;
            for (int t = 0; t < ntile && nt < MAX_TILES; t++) {
                meta[1 + nt] = k;
                meta[1 + MAX_TILES + nt] = running + t * BM;
                nt++;
            }
            running += ntile * BM;
        }
        meta[0] = nt;
    }
}

// ---------------------------------------------------------------------------
// Dispatch 3: wave-aggregated scatter into branch-grouped order + out init.
// ---------------------------------------------------------------------------
__global__ void __launch_bounds__(256)
scatter_kernel(const int* __restrict__ kidx,
               int* __restrict__ cursors,
               const float* __restrict__ c2s,
               int* __restrict__ order,
               float* __restrict__ out)
{
    const int b = blockIdx.x * 256 + threadIdx.x;   // 0..4095, all active
    const int lane = threadIdx.x & 63;
    const int k = kidx[b] & 7;
    out[b] = c2s[k];

    const unsigned long long below = (lane == 63) ? ~0ull >> 1
                                   : ((1ull << lane) - 1);
    int pos = 0;
#pragma unroll
    for (int kk = 0; kk < NK; kk++) {
        unsigned long long m = __ballot(k == kk);
        if (m) {
            int leader = __ffsll((long long)m) - 1;
            int base = 0;
            if (lane == leader) base = atomicAdd(&cursors[kk], __popcll(m));
            base = __shfl(base, leader, 64);
            if (k == kk) pos = base + __popcll(m & below);
        }
    }
    if (pos >= 0 && pos < MAX_ROWS) order[pos] = b;
}

// ---------------------------------------------------------------------------
// Dispatch 4: per-branch bf16 GEMM + fused epilogue (128x128, 2x2 waves,
// BK=32 -- the proven R1 geometry) with depth-1 double-buffer prefetch.
// Per K-step: STAGE(next tile) -> COMPUTE(current) -> __syncthreads.
// The barrier's vmcnt(0) drain lands AFTER the compute phase, so the next
// tile's load latency is covered by the current tile's ds_read+MFMA.
// Epilogue: +b1, relu, *W3, 16-lane reduce, atomicAdd into out.
// ---------------------------------------------------------------------------
#define STAGE(aB, bB, kkel)                                                         \
    do {                                                                            \
        __builtin_amdgcn_global_load_lds(                                           \
            (const __attribute__((address_space(1))) void*)(pa0 + (kkel)),          \
            (__attribute__((address_space(3))) void*)((aB) + wid * 512), 16, 0, 0); \
        __builtin_amdgcn_global_load_lds(                                           \
            (const __attribute__((address_space(1))) void*)(pa1 + (kkel)),          \
            (__attribute__((address_space(3))) void*)((aB) + 2048 + wid * 512), 16, 0, 0); \
        __builtin_amdgcn_global_load_lds(                                           \
            (const __attribute__((address_space(1))) void*)(pb0 + (kkel)),          \
            (__attribute__((address_space(3))) void*)((bB) + wid * 512), 16, 0, 0); \
        __builtin_amdgcn_global_load_lds(                                           \
            (const __attribute__((address_space(1))) void*)(pb1 + (kkel)),          \
            (__attribute__((address_space(3))) void*)((bB) + 2048 + wid * 512), 16, 0, 0); \
    } while (0)

#define COMPUTE(aB, bB)                                                             \
    do {                                                                            \
        bf16x8 af[4], bfv[4];                                                       \
        _Pragma("unroll")                                                           \
        for (int i = 0; i < 4; i++) {                                               \
            af[i]  = *(const bf16x8*)((aB) + (wm * 64 + i * 16 + mrow) * BK + qk);  \
            bfv[i] = *(const bf16x8*)((bB) + (wn * 64 + i * 16 + mrow) * BK + qk);  \
        }                                                                           \
        _Pragma("unroll")                                                           \
        for (int i = 0; i < 4; i++)                                                 \
            _Pragma("unroll")                                                       \
            for (int j = 0; j < 4; j++)                                             \
                acc[i][j] = __builtin_amdgcn_mfma_f32_16x16x32_bf16(                \
                    af[i], bfv[j], acc[i][j], 0, 0, 0);                             \
    } while (0)

__global__ void __launch_bounds__(256)
gemm_kernel(const bf16* __restrict__ xc,
            const bf16* __restrict__ Wb,
            const int* __restrict__ order,
            const int* __restrict__ meta,
            const float* __restrict__ b1,
            const float* __restrict__ W3,
            float* __restrict__ out)
{
    int n_mt = meta[0];
    if (n_mt > MAX_TILES) n_mt = MAX_TILES;
    const int mt = blockIdx.y;
    if (mt >= n_mt) return;
    const int kbr = meta[1 + mt] & 7;
    int row0 = meta[1 + MAX_TILES + mt];
    if (row0 < 0) row0 = 0;
    if (row0 > MAX_ROWS - BM) row0 = MAX_ROWS - BM;
    const int col0 = blockIdx.x * BN;

    __shared__ bf16 As0[BM * BK];   // 8 KB each; two constant-address buffers
    __shared__ bf16 As1[BM * BK];
    __shared__ bf16 Bs0[BN * BK];
    __shared__ bf16 Bs1[BN * BK];
    __shared__ int rowb[BM];

    const int tid = threadIdx.x;
    const int lane = tid & 63;
    const int wid = tid >> 6;
    const int wm = wid >> 1;
    const int wn = wid & 1;

    if (tid < BM) {
        int b = order[row0 + tid];
        rowb[tid] = (b >= 0 && b < NB) ? b : -1;
    }
    __syncthreads();

    const int srow = tid >> 2;            // 0..63
    const int scol = (tid & 3) * 8;
    const int ra0 = rowb[srow];
    const int ra1 = rowb[64 + srow];
    const bf16* pa0 = xc + (size_t)(ra0 < 0 ? 0 : ra0) * ND + scol;
    const bf16* pa1 = xc + (size_t)(ra1 < 0 ? 0 : ra1) * ND + scol;
    // interleaved Wb: W1-row for output col d, branch k sits at row d*NK+k
    const bf16* pb0 = Wb + ((size_t)(col0 + srow) * NK + kbr) * ND + scol;
    const bf16* pb1 = pb0 + (size_t)64 * NK * ND;

    floatx4 zero = {0.f, 0.f, 0.f, 0.f};
    floatx4 acc[4][4];
#pragma unroll
    for (int i = 0; i < 4; i++)
#pragma unroll
        for (int j = 0; j < 4; j++) acc[i][j] = zero;

    const int qk = (lane >> 4) * 8;
    const int mrow = lane & 15;

    // prologue: stage tile 0 into buffer 0, drain
    STAGE(As0, Bs0, 0);
    __syncthreads();

    // 2x-unrolled: buffer addresses are compile-time constants
    for (int kk = 0; kk < ND; kk += 2 * BK) {
        if (kk + BK < ND) STAGE(As1, Bs1, kk + BK);
        COMPUTE(As0, Bs0);
        __syncthreads();                  // drains As1/Bs1 loads (post-compute)
        if (kk + 2 * BK < ND) STAGE(As0, Bs0, kk + 2 * BK);
        COMPUTE(As1, Bs1);
        __syncthreads();                  // drains As0/Bs0 loads
    }

    // Epilogue. C/D layout: col = lane&15, row = (lane>>4)*4 + reg.
    const int colq = lane & 15;
    const int quad = lane >> 4;
    float bias[4], w3v[4];
#pragma unroll
    for (int j = 0; j < 4; j++) {
        int d = col0 + wn * 64 + j * 16 + colq;
        bias[j] = b1[d * NK + kbr];
        w3v[j] = W3[d];
    }
#pragma unroll
    for (int i = 0; i < 4; i++) {
#pragma unroll
        for (int r = 0; r < 4; r++) {
            float s = 0.f;
#pragma unroll
            for (int j = 0; j < 4; j++) {
                float v = acc[i][j][r] + bias[j];
                s += (v > 0.f) ? v * w3v[j] : 0.f;
            }
#pragma unroll
            for (int m = 1; m < 16; m <<= 1) s += __shfl_xor(s, m, 64);
            if (colq == 0) {
                int b = rowb[wm * 64 + i * 16 + quad * 4 + r];
                if (b >= 0) atomicAdd(out + b, s);
            }
        }
    }
}

// ---------------------------------------------------------------------------
extern "C" void kernel_launch(void* const* d_in, const int* in_sizes, int n_in,
                              void* d_out, int out_size, void* d_ws, size_t ws_size,
                              hipStream_t stream)
{
    const float* x         = (const float*)d_in[0];
    const float* intention = (const float*)d_in[1];
    const float* W1        = (const float*)d_in[2];
    const float* b1        = (const float*)d_in[3];
    const float* W2        = (const float*)d_in[4];
    const float* b2        = (const float*)d_in[5];
    const float* W3        = (const float*)d_in[6];
    const float* b3        = (const float*)d_in[7];
    float* out = (float*)d_out;

    char* ws = (char*)d_ws;
    int*   kidx    = (int*)(ws + OFF_KIDX);
    int*   order   = (int*)(ws + OFF_ORDER);
    int*   meta    = (int*)(ws + OFF_META);
    int*   cursors = (int*)(ws + OFF_CUR);
    float* c2s     = (float*)(ws + OFF_C2S);
    int*   cntp    = (int*)(ws + OFF_CNTP);
    bf16*  xc      = (bf16*)(ws + OFF_XC);
    bf16*  Wb      = (bf16*)(ws + OFF_WB);

    prep_conv_kernel<<<dim3(PREP_GRID), dim3(256), 0, stream>>>(
        x, intention, W1, kidx, cntp, xc, Wb);
    meta_kernel<<<dim3(1), dim3(256), 0, stream>>>(
        cntp, W2, b2, W3, b3, meta, cursors, c2s);
    scatter_kernel<<<dim3(NB / 256), dim3(256), 0, stream>>>(
        kidx, cursors, c2s, order, out);
    gemm_kernel<<<dim3(ND / BN, MAX_TILES), dim3(256), 0, stream>>>(
        xc, Wb, order, meta, b1, W3, out);
}

// Round 6
// 317.976 us; speedup vs baseline: 1.0856x; 1.0856x over previous
//
#include <hip/hip_runtime.h>
#include <hip/hip_bf16.h>
#include <stdint.h>

// Problem constants (B=4096, D=2048, K=8, H2=64)
#define NB 4096
#define ND 2048
#define NK 8
#define NH 64

// GEMM tile: 128x128, BK=32, 16x16x32 bf16 MFMA, 256 threads (4 waves, 2x2).
// Exact R1 two-barrier loop. B-side is reg-staged DIRECTLY from W1 fp32
// (load dwordx4 -> cvt bf16 -> ds_write_b128): the fp32->bf16 W conversion
// rides in the gemm's latency slack instead of a dedicated 77us prep pass.
// A-side unchanged (global_load_lds from xc, row-gathered).
#define BM 128
#define BN 128
#define BK 32
#define MAX_ROWS 5120   // 4096 + 8*127 padding worst case
#define MAX_TILES 40

// prep grid: 4096 x-convert blocks (8 floats/thread, m146 pattern) + 16 kidx
#define CONV_BLOCKS  4096
#define KIDX_BLOCKS  (NB / 256)    // 16: kidx + per-block histogram
#define PREP_GRID    (CONV_BLOCKS + KIDX_BLOCKS)

typedef __bf16 bf16;
typedef __bf16 bf16x8 __attribute__((ext_vector_type(8)));
typedef float floatx4 __attribute__((ext_vector_type(4)));

// Workspace layout (bytes) -- Wb is GONE (W1 consumed fp32 in the gemm)
#define OFF_KIDX   0u          // 4096 int
#define OFF_ORDER  16384u      // 5120 int (padding slots stay poisoned -> negative)
#define OFF_META   40960u      // 81 ints: [0]=n_mt, [1..40]=branch, [41..80]=row0
#define OFF_CUR    41472u      // 8 int cursors
#define OFF_C2S    41536u      // 8 float
#define OFF_CNTP   41600u      // 16*8 int per-block partial counts
#define OFF_XC     65536u      // 4096*2048 bf16 = 16777216 B

// Convert 8 consecutive floats -> bf16x8.
__device__ inline bf16x8 cvt8(const float* __restrict__ src) {
    float4 a = *(const float4*)(src);
    float4 c = *(const float4*)(src + 4);
    bf16x8 v;
    v[0] = (bf16)a.x; v[1] = (bf16)a.y; v[2] = (bf16)a.z; v[3] = (bf16)a.w;
    v[4] = (bf16)c.x; v[5] = (bf16)c.y; v[6] = (bf16)c.z; v[7] = (bf16)c.w;
    return v;
}

// ---------------------------------------------------------------------------
// Dispatch 1: x->xc bf16 (32B/lane reads, 16B/lane contiguous writes) +
// kidx + per-block branch histograms. ~50 MB total traffic.
// ---------------------------------------------------------------------------
__global__ void __launch_bounds__(256)
prep_conv_kernel(const float* __restrict__ x,
                 const float* __restrict__ intention,
                 int* __restrict__ kidx,
                 int* __restrict__ cntp,
                 bf16* __restrict__ xc)
{
    const int blk = blockIdx.x;
    const int tid = threadIdx.x;

    if (blk < CONV_BLOCKS) {
        const size_t g = ((size_t)blk * 256 + tid) * 8;
        *(bf16x8*)(xc + g) = cvt8(x + g);
    } else {
        __shared__ int h[NK];
        const int hb = blk - CONV_BLOCKS;                  // 0..15
        if (tid < NK) h[tid] = 0;
        __syncthreads();
        const int b = hb * 256 + tid;
        float4 a = *(const float4*)(intention + (size_t)b * NK);
        float4 c = *(const float4*)(intention + (size_t)b * NK + 4);
        int k = 0;
        if (a.y > 0.5f) k = 1;
        if (a.z > 0.5f) k = 2;
        if (a.w > 0.5f) k = 3;
        if (c.x > 0.5f) k = 4;
        if (c.y > 0.5f) k = 5;
        if (c.z > 0.5f) k = 6;
        if (c.w > 0.5f) k = 7;
        kidx[b] = k;
        atomicAdd(&h[k], 1);
        __syncthreads();
        if (tid < NK) cntp[hb * NK + tid] = h[tid];
    }
}

// ---------------------------------------------------------------------------
// Dispatch 2: single small block. Sum partial counts, build M-tile table +
// branch base cursors; wave 1 computes c2s[k] = b3 + sum_h relu(W2+b2)*W3.
// ---------------------------------------------------------------------------
__global__ void __launch_bounds__(256)
meta_kernel(const int* __restrict__ cntp,
            const float* __restrict__ W2,
            const float* __restrict__ b2,
            const float* __restrict__ W3,
            const float* __restrict__ b3,
            int* __restrict__ meta,
            int* __restrict__ cursors,
            float* __restrict__ c2s)
{
    __shared__ int cnt[NK];
    const int tid = threadIdx.x;
    if (tid < NK) {
        int s = 0;
#pragma unroll
        for (int i = 0; i < KIDX_BLOCKS; i++) s += cntp[i * NK + tid];
        cnt[tid] = s;
    }
    if (tid >= 64 && tid < 128) {
        const int l = tid - 64;
        const int k = l & 7;
        const int hc = l >> 3;
        float s = 0.f;
#pragma unroll
        for (int j = 0; j < 8; j++) {
            int h = hc * 8 + j;
            float v = W2[h * NK + k] + b2[h];
            if (v > 0.f) s += v * W3[ND + h];
        }
        s += __shfl_xor(s, 8, 64);
        s += __shfl_xor(s, 16, 64);
        s += __shfl_xor(s, 32, 64);
        if (l < 8) c2s[k] = s + b3[0];
    }
    __syncthreads();
    if (tid == 0) {
        int running = 0, nt = 0;
        for (int k = 0; k < NK; k++) {
            cursors[k] = running;
            int ntile = (cnt[k] + BM - 1) / BM;
            for (int t = 0; t < ntile && nt < MAX_TILES; t++) {
                meta[1 + nt] = k;
                meta[1 + MAX_TILES + nt] = running + t * BM;
                nt++;
            }
            running += ntile * BM;
        }
        meta[0] = nt;
    }
}

// ---------------------------------------------------------------------------
// Dispatch 3: wave-aggregated scatter into branch-grouped order + out init.
// ---------------------------------------------------------------------------
__global__ void __launch_bounds__(256)
scatter_kernel(const int* __restrict__ kidx,
               int* __restrict__ cursors,
               const float* __restrict__ c2s,
               int* __restrict__ order,
               float* __restrict__ out)
{
    const int b = blockIdx.x * 256 + threadIdx.x;   // 0..4095, all active
    const int lane = threadIdx.x & 63;
    const int k = kidx[b] & 7;
    out[b] = c2s[k];

    const unsigned long long below = (lane == 63) ? ~0ull >> 1
                                   : ((1ull << lane) - 1);
    int pos = 0;
#pragma unroll
    for (int kk = 0; kk < NK; kk++) {
        unsigned long long m = __ballot(k == kk);
        if (m) {
            int leader = __ffsll((long long)m) - 1;
            int base = 0;
            if (lane == leader) base = atomicAdd(&cursors[kk], __popcll(m));
            base = __shfl(base, leader, 64);
            if (k == kk) pos = base + __popcll(m & below);
        }
    }
    if (pos >= 0 && pos < MAX_ROWS) order[pos] = b;
}

// ---------------------------------------------------------------------------
// Dispatch 4: per-branch GEMM + fused epilogue (exact R1 two-barrier loop).
// A: global_load_lds from xc (bf16, row-gathered). B: reg-staged from W1
// fp32 -- per thread 4x dwordx4 (rows srow, srow+64; 32B each), cvt to
// 2x bf16x8, 2x ds_write_b128 into the same Bs layout COMPUTE always used.
// Barrier drains vmcnt (A glls) + lgkmcnt (B ds_writes) exactly as before.
// Epilogue: +b1, relu, *W3, 16-lane reduce, atomicAdd into out.
// ---------------------------------------------------------------------------
__global__ void __launch_bounds__(256)
gemm_kernel(const bf16* __restrict__ xc,
            const float* __restrict__ W1,
            const int* __restrict__ order,
            const int* __restrict__ meta,
            const float* __restrict__ b1,
            const float* __restrict__ W3,
            float* __restrict__ out)
{
    int n_mt = meta[0];
    if (n_mt > MAX_TILES) n_mt = MAX_TILES;
    const int mt = blockIdx.y;
    if (mt >= n_mt) return;
    const int kbr = meta[1 + mt] & 7;
    int row0 = meta[1 + MAX_TILES + mt];
    if (row0 < 0) row0 = 0;
    if (row0 > MAX_ROWS - BM) row0 = MAX_ROWS - BM;
    const int col0 = blockIdx.x * BN;

    __shared__ bf16 As[BM * BK];   // 8 KB row-major, 64B row stride
    __shared__ bf16 Bs[BN * BK];   // 8 KB
    __shared__ int rowb[BM];

    const int tid = threadIdx.x;
    const int lane = tid & 63;
    const int wid = tid >> 6;
    const int wm = wid >> 1;
    const int wn = wid & 1;

    if (tid < BM) {
        int b = order[row0 + tid];
        rowb[tid] = (b >= 0 && b < NB) ? b : -1;
    }
    __syncthreads();

    const int srow = tid >> 2;            // 0..63
    const int scol = (tid & 3) * 8;       // element offset (bf16 or fp32)
    const int ra0 = rowb[srow];
    const int ra1 = rowb[64 + srow];
    const bf16* pa0 = xc + (size_t)(ra0 < 0 ? 0 : ra0) * ND + scol;
    const bf16* pa1 = xc + (size_t)(ra1 < 0 ? 0 : ra1) * ND + scol;
    // B source: W1 fp32, row for output col d / branch k is d*NK+k
    const float* pw0 = W1 + ((size_t)(col0 + srow) * NK + kbr) * ND + scol;
    const float* pw1 = pw0 + (size_t)64 * NK * ND;
    bf16* la0 = As + wid * 512;           // wave-uniform LDS bases (elements)
    bf16* la1 = As + 2048 + wid * 512;
    bf16* lb0 = Bs + srow * BK + scol;            // per-lane B write slots
    bf16* lb1 = Bs + (64 + srow) * BK + scol;

    floatx4 zero = {0.f, 0.f, 0.f, 0.f};
    floatx4 acc[4][4];
#pragma unroll
    for (int i = 0; i < 4; i++)
#pragma unroll
        for (int j = 0; j < 4; j++) acc[i][j] = zero;

    const int qk = (lane >> 4) * 8;
    const int mrow = lane & 15;

    for (int kk = 0; kk < ND; kk += BK) {
        // B loads first (longest latency), then A DMA, then cvt+ds_write.
        float4 b0a = *(const float4*)(pw0 + kk);
        float4 b0b = *(const float4*)(pw0 + kk + 4);
        float4 b1a = *(const float4*)(pw1 + kk);
        float4 b1b = *(const float4*)(pw1 + kk + 4);
        __builtin_amdgcn_global_load_lds(
            (const __attribute__((address_space(1))) void*)(pa0 + kk),
            (__attribute__((address_space(3))) void*)la0, 16, 0, 0);
        __builtin_amdgcn_global_load_lds(
            (const __attribute__((address_space(1))) void*)(pa1 + kk),
            (__attribute__((address_space(3))) void*)la1, 16, 0, 0);
        bf16x8 w0, w1;
        w0[0] = (bf16)b0a.x; w0[1] = (bf16)b0a.y; w0[2] = (bf16)b0a.z; w0[3] = (bf16)b0a.w;
        w0[4] = (bf16)b0b.x; w0[5] = (bf16)b0b.y; w0[6] = (bf16)b0b.z; w0[7] = (bf16)b0b.w;
        w1[0] = (bf16)b1a.x; w1[1] = (bf16)b1a.y; w1[2] = (bf16)b1a.z; w1[3] = (bf16)b1a.w;
        w1[4] = (bf16)b1b.x; w1[5] = (bf16)b1b.y; w1[6] = (bf16)b1b.z; w1[7] = (bf16)b1b.w;
        *(bf16x8*)lb0 = w0;
        *(bf16x8*)lb1 = w1;
        __syncthreads();

        bf16x8 af[4], bfv[4];
#pragma unroll
        for (int i = 0; i < 4; i++) {
            af[i]  = *(const bf16x8*)(As + (wm * 64 + i * 16 + mrow) * BK + qk);
            bfv[i] = *(const bf16x8*)(Bs + (wn * 64 + i * 16 + mrow) * BK + qk);
        }
#pragma unroll
        for (int i = 0; i < 4; i++)
#pragma unroll
            for (int j = 0; j < 4; j++)
                acc[i][j] = __builtin_amdgcn_mfma_f32_16x16x32_bf16(
                    af[i], bfv[j], acc[i][j], 0, 0, 0);
        __syncthreads();
    }

    // Epilogue. C/D layout: col = lane&15, row = (lane>>4)*4 + reg.
    const int colq = lane & 15;
    const int quad = lane >> 4;
    float bias[4], w3v[4];
#pragma unroll
    for (int j = 0; j < 4; j++) {
        int d = col0 + wn * 64 + j * 16 + colq;
        bias[j] = b1[d * NK + kbr];
        w3v[j] = W3[d];
    }
#pragma unroll
    for (int i = 0; i < 4; i++) {
#pragma unroll
        for (int r = 0; r < 4; r++) {
            float s = 0.f;
#pragma unroll
            for (int j = 0; j < 4; j++) {
                float v = acc[i][j][r] + bias[j];
                s += (v > 0.f) ? v * w3v[j] : 0.f;
            }
#pragma unroll
            for (int m = 1; m < 16; m <<= 1) s += __shfl_xor(s, m, 64);
            if (colq == 0) {
                int b = rowb[wm * 64 + i * 16 + quad * 4 + r];
                if (b >= 0) atomicAdd(out + b, s);
            }
        }
    }
}

// ---------------------------------------------------------------------------
extern "C" void kernel_launch(void* const* d_in, const int* in_sizes, int n_in,
                              void* d_out, int out_size, void* d_ws, size_t ws_size,
                              hipStream_t stream)
{
    const float* x         = (const float*)d_in[0];
    const float* intention = (const float*)d_in[1];
    const float* W1        = (const float*)d_in[2];
    const float* b1        = (const float*)d_in[3];
    const float* W2        = (const float*)d_in[4];
    const float* b2        = (const float*)d_in[5];
    const float* W3        = (const float*)d_in[6];
    const float* b3        = (const float*)d_in[7];
    float* out = (float*)d_out;

    char* ws = (char*)d_ws;
    int*   kidx    = (int*)(ws + OFF_KIDX);
    int*   order   = (int*)(ws + OFF_ORDER);
    int*   meta    = (int*)(ws + OFF_META);
    int*   cursors = (int*)(ws + OFF_CUR);
    float* c2s     = (float*)(ws + OFF_C2S);
    int*   cntp    = (int*)(ws + OFF_CNTP);
    bf16*  xc      = (bf16*)(ws + OFF_XC);

    prep_conv_kernel<<<dim3(PREP_GRID), dim3(256), 0, stream>>>(
        x, intention, kidx, cntp, xc);
    meta_kernel<<<dim3(1), dim3(256), 0, stream>>>(
        cntp, W2, b2, W3, b3, meta, cursors, c2s);
    scatter_kernel<<<dim3(NB / 256), dim3(256), 0, stream>>>(
        kidx, cursors, c2s, order, out);
    gemm_kernel<<<dim3(ND / BN, MAX_TILES), dim3(256), 0, stream>>>(
        xc, W1, order, meta, b1, W3, out);
}